// Round 14
// baseline (1055.634 us; speedup 1.0000x reference)
//
#include <hip/hip_runtime.h>
#include <stdint.h>

#define DEVI __device__ __forceinline__
#define FENCE() asm volatile("" ::: "memory")
#define BAR() do{ FENCE(); __builtin_amdgcn_s_barrier(); FENCE(); }while(0)

typedef short short8 __attribute__((ext_vector_type(8)));
typedef short short4v __attribute__((ext_vector_type(4)));
typedef float f32x4 __attribute__((ext_vector_type(4)));

DEVI float bf2f(unsigned short s){ union{unsigned u; float f;} x; x.u = ((unsigned)s)<<16; return x.f; }
DEVI unsigned short f2bf(float f){ union{float f; unsigned u;} x; x.f=f; unsigned r = x.u + 0x7fff + ((x.u>>16)&1); return (unsigned short)(r>>16); }

DEVI void gload_lds16(const void* g, void* l){
  __builtin_amdgcn_global_load_lds((const __attribute__((address_space(1))) unsigned int*)g,
                                   (__attribute__((address_space(3))) unsigned int*)l, 16, 0, 0);
}

// ---------------------------------------------------------------------------
// Merged weight-prep kernel, 8-tile blocks for 8x memory-level parallelism.
__global__ __launch_bounds__(256)
void prep_all(const float* __restrict__ caw, const float* __restrict__ cpw,
              const float* __restrict__ w_in, const float* __restrict__ w1,
              const float* __restrict__ w2, const float* __restrict__ w_out,
              unsigned short* __restrict__ wT_attn, unsigned short* __restrict__ wT_proj,
              unsigned short* __restrict__ wT_in, unsigned short* __restrict__ wT1p,
              unsigned short* __restrict__ wT_2, unsigned short* __restrict__ wT_out,
              const float* __restrict__ x, const float* __restrict__ gw,
              const float* __restrict__ bw, unsigned short* __restrict__ xn)
{
  __shared__ float tile[8][32][33];
  int bid = blockIdx.x;
  int t = threadIdx.x;
  int tr = t>>3, tc = (t&7)*4;

  const float* src = nullptr; unsigned short* dst = nullptr;
  int K=0, N=0, kb=0, nb0=0;

  if (bid < 96){                     // attn W: K=512,N=1536, nx8=6, ny=16
    int xb8 = bid % 6, yb = bid / 6;
    src = caw; dst = wT_attn; K=512; N=1536; kb=yb*32; nb0=xb8*256;
  } else if ((bid -= 96) < 32){      // proj: 512x512, nx8=2, ny=16
    int xb8 = bid % 2, yb = bid / 2;
    src = cpw; dst = wT_proj; K=512; N=512; kb=yb*32; nb0=xb8*256;
  } else if ((bid -= 32) < 2048){    // w_in: K=512,N=2048, nx8=8, ny=16, z=16
    int z = bid >> 7, r = bid & 127;
    int xb8 = r % 8, yb = r / 8;
    src = w_in + (size_t)z*512*2048; dst = wT_in + (size_t)z*2048*512;
    K=512; N=2048; kb=yb*32; nb0=xb8*256;
  } else if ((bid -= 2048) < 16384){ // w1 permuted: nx8=16, ny=64, z=16
    int z = bid >> 10, r = bid & 1023;
    int xb8 = r % 16, yb = r / 16;
    const float* s1 = w1 + (size_t)z*2048*4096;
    unsigned short* d1 = wT1p + (size_t)z*4096*2048;
    int k0 = yb*32;
    float4 v[8];
    #pragma unroll
    for (int j=0;j<8;j++){
      int g = xb8*8 + j;
      int srccol = (tc < 16) ? (g*16 + tc) : (2048 + g*16 + (tc-16));
      v[j] = *(const float4*)(s1 + (size_t)(k0+tr)*4096 + srccol);
    }
    #pragma unroll
    for (int j=0;j<8;j++){
      tile[j][tr][tc+0]=v[j].x; tile[j][tr][tc+1]=v[j].y;
      tile[j][tr][tc+2]=v[j].z; tile[j][tr][tc+3]=v[j].w;
    }
    __syncthreads();
    #pragma unroll
    for (int j=0;j<8;j++){
      int np0 = xb8*256 + 32*j;
      short4v ov;
      ov[0] = (short)f2bf(tile[j][tc+0][tr]);
      ov[1] = (short)f2bf(tile[j][tc+1][tr]);
      ov[2] = (short)f2bf(tile[j][tc+2][tr]);
      ov[3] = (short)f2bf(tile[j][tc+3][tr]);
      *(short4v*)(d1 + (size_t)(np0+tr)*2048 + k0 + tc) = ov;
    }
    return;
  } else if ((bid -= 16384) < 8192){ // w2: 2048x2048, nx8=8, ny=64, z=16
    int z = bid >> 9, r = bid & 511;
    int xb8 = r % 8, yb = r / 8;
    src = w2 + (size_t)z*2048*2048; dst = wT_2 + (size_t)z*2048*2048;
    K=2048; N=2048; kb=yb*32; nb0=xb8*256;
  } else if ((bid -= 8192) < 2048){  // w_out: K=2048,N=512, nx8=2, ny=64, z=16
    int z = bid >> 7, r = bid & 127;
    int xb8 = r % 2, yb = r / 2;
    src = w_out + (size_t)z*2048*512; dst = wT_out + (size_t)z*512*2048;
    K=2048; N=512; kb=yb*32; nb0=xb8*256;
  } else {                           // rmsnorm: 512 blocks x 4 rows
    bid -= 2048;
    int row = bid*4 + (t>>6);
    int lane = t & 63;
    const float* xr = x + (size_t)row*512 + lane*8;
    float4 a = *(const float4*)xr;
    float4 c = *(const float4*)(xr+4);
    float ss = a.x*a.x+a.y*a.y+a.z*a.z+a.w*a.w + c.x*c.x+c.y*c.y+c.z*c.z+c.w*c.w;
    #pragma unroll
    for (int m=1;m<64;m<<=1) ss += __shfl_xor(ss, m);
    float inv = 1.0f / sqrtf(ss*(1.f/512.f) + 1e-6f);
    const float* gr = gw + lane*8; const float* br = bw + lane*8;
    float4 g0=*(const float4*)gr, g1=*(const float4*)(gr+4);
    float4 b0=*(const float4*)br, b1=*(const float4*)(br+4);
    short8 o;
    o[0]=(short)f2bf(a.x*inv*g0.x + b0.x);
    o[1]=(short)f2bf(a.y*inv*g0.y + b0.y);
    o[2]=(short)f2bf(a.z*inv*g0.z + b0.z);
    o[3]=(short)f2bf(a.w*inv*g0.w + b0.w);
    o[4]=(short)f2bf(c.x*inv*g1.x + b1.x);
    o[5]=(short)f2bf(c.y*inv*g1.y + b1.y);
    o[6]=(short)f2bf(c.z*inv*g1.z + b1.z);
    o[7]=(short)f2bf(c.w*inv*g1.w + b1.w);
    *(short8*)(xn + (size_t)row*512 + lane*8) = o;
    return;
  }
  {
    float4 v[8];
    #pragma unroll
    for (int j=0;j<8;j++)
      v[j] = *(const float4*)(src + (size_t)(kb+tr)*N + nb0 + 32*j + tc);
    #pragma unroll
    for (int j=0;j<8;j++){
      tile[j][tr][tc+0]=v[j].x; tile[j][tr][tc+1]=v[j].y;
      tile[j][tr][tc+2]=v[j].z; tile[j][tr][tc+3]=v[j].w;
    }
    __syncthreads();
    #pragma unroll
    for (int j=0;j<8;j++){
      short4v ov;
      ov[0] = (short)f2bf(tile[j][tc+0][tr]);
      ov[1] = (short)f2bf(tile[j][tc+1][tr]);
      ov[2] = (short)f2bf(tile[j][tc+2][tr]);
      ov[3] = (short)f2bf(tile[j][tc+3][tr]);
      *(short4v*)(dst + (size_t)(nb0+32*j+tr)*K + kb + tc) = ov;
    }
  }
}

// ---------------------------------------------------------------------------
// Expert GEMM: m97-lineage 128x128 2-barrier engine, 32 KB LDS (~3-5 blk/CU
// -> implicit inter-block overlap of barrier stalls). Batched over z via off[].
// EPI: 1 = bf16 out + bias; 2 = fused SwiGLU (permuted W1, N=4096 acc ->
//      2048-col bf16 out; bias[0..2047]=a, [2048..4095]=gate)
template<int EPI>
__global__ __launch_bounds__(256)
void gemmE(const unsigned short* __restrict__ A, const unsigned short* __restrict__ B,
           const float* __restrict__ bias,
           unsigned short* __restrict__ Ch,
           int N, int K,
           const int* __restrict__ off, long long strideBz, long long strideBiasz)
{
  __shared__ char smem[32768];
  char* smA = smem; char* smB = smem + 16384;
  int z = blockIdx.z;
  int rowbase = off[z], Mz = off[z+1] - rowbase;
  int row0 = blockIdx.y * 128;
  if (row0 >= Mz) return;
  int col0 = blockIdx.x * 128;
  const unsigned short* Ab = A + (size_t)(rowbase + row0) * K;
  const unsigned short* Bb = B + (size_t)z * strideBz + (size_t)col0 * K;
  const float* biasz = bias + (size_t)z * strideBiasz;

  int t = threadIdx.x, w = t>>6, lane = t&63;
  int lrow = lane&15, lg = lane>>4;
  int wr = w>>1, wc = w&1;

  f32x4 acc[4][4];
  #pragma unroll
  for (int i=0;i<4;i++){
    #pragma unroll
    for (int j=0;j<4;j++) acc[i][j] = f32x4{0.f,0.f,0.f,0.f};
  }
  int nkt = K >> 6;
  for (int kt=0; kt<nkt; kt++){
    __syncthreads();
    int k0 = kt*64;
    #pragma unroll
    for (int i=0;i<4;i++){
      int s = (i*4 + w)*64 + lane;
      int r = s>>3;
      int kb = (s&7) ^ (r&7);
      gload_lds16(Ab + (size_t)r*K + k0 + kb*8, smA + (size_t)(i*4+w)*1024);
      gload_lds16(Bb + (size_t)r*K + k0 + kb*8, smB + (size_t)(i*4+w)*1024);
    }
    __syncthreads();
    #pragma unroll
    for (int ks=0; ks<2; ks++){
      short8 af[4], bf[4];
      int kbb = lg + ks*4;
      #pragma unroll
      for (int m=0;m<4;m++){
        int rt = wr*64 + m*16 + lrow;
        af[m] = *(const short8*)(smA + rt*128 + ((kbb ^ (rt&7))<<4));
      }
      #pragma unroll
      for (int n=0;n<4;n++){
        int rt = wc*64 + n*16 + lrow;
        bf[n] = *(const short8*)(smB + rt*128 + ((kbb ^ (rt&7))<<4));
      }
      #pragma unroll
      for (int m=0;m<4;m++){
        #pragma unroll
        for (int n=0;n<4;n++)
          acc[m][n] = __builtin_amdgcn_mfma_f32_16x16x32_bf16(af[m], bf[n], acc[m][n], 0,0,0);
      }
    }
  }
  #pragma unroll
  for (int m=0;m<4;m++){
    #pragma unroll
    for (int j=0;j<4;j++){
      int row = row0 + wr*64 + m*16 + lg*4 + j;
      if (row < Mz){
        size_t rg = (size_t)(rowbase + row);
        if constexpr (EPI == 2){
          #pragma unroll
          for (int nf=0;nf<4;nf+=2){
            int pcol = col0 + wc*64 + nf*16;
            int scol = ((pcol>>5)<<4) + lrow;
            float av = acc[m][nf][j]   + biasz[scol];
            float gv = acc[m][nf+1][j] + biasz[2048 + scol];
            float sg = gv / (1.f + __expf(-gv));
            Ch[rg*2048 + scol] = f2bf(av * sg);
          }
        } else {
          #pragma unroll
          for (int n=0;n<4;n++){
            int col = col0 + wc*64 + n*16 + lrow;
            float v = acc[m][n][j] + biasz[col];
            Ch[rg * N + col] = f2bf(v);
          }
        }
      }
    }
  }
}

// ---------------------------------------------------------------------------
// 128x128 GEMM with fused qkv head-norm epilogue.
__global__ __launch_bounds__(256)
void gemm_qkv(const unsigned short* __restrict__ A, const unsigned short* __restrict__ B,
              const float* __restrict__ bias, const float* __restrict__ alpha,
              unsigned short* __restrict__ oq, unsigned short* __restrict__ ok,
              unsigned short* __restrict__ ov, int N, int K)
{
  __shared__ char smem[32768];
  char* smA = smem; char* smB = smem + 16384;
  int row0 = blockIdx.y * 128;
  int col0 = blockIdx.x * 128;
  int t = threadIdx.x, w = t>>6, lane = t&63;
  int lrow = lane&15, lg = lane>>4;
  int wr = w>>1, wc = w&1;

  f32x4 acc[4][4];
  #pragma unroll
  for (int i=0;i<4;i++){
    #pragma unroll
    for (int j=0;j<4;j++) acc[i][j] = f32x4{0.f,0.f,0.f,0.f};
  }
  const size_t Abase = (size_t)row0 * K;
  const size_t Bbase = (size_t)col0 * K;
  int nkt = K >> 6;
  for (int kt=0; kt<nkt; kt++){
    __syncthreads();
    int k0 = kt*64;
    #pragma unroll
    for (int i=0;i<4;i++){
      int s = (i*4 + w)*64 + lane;
      int r = s>>3;
      int kb = (s&7) ^ (r&7);
      gload_lds16(A + Abase + (size_t)r*K + k0 + kb*8, smA + (size_t)(i*4+w)*1024);
      gload_lds16(B + Bbase + (size_t)r*K + k0 + kb*8, smB + (size_t)(i*4+w)*1024);
    }
    __syncthreads();
    #pragma unroll
    for (int ks=0; ks<2; ks++){
      short8 af[4], bf[4];
      int kbb = lg + ks*4;
      #pragma unroll
      for (int m=0;m<4;m++){
        int rt = wr*64 + m*16 + lrow;
        af[m] = *(const short8*)(smA + rt*128 + ((kbb ^ (rt&7))<<4));
      }
      #pragma unroll
      for (int n=0;n<4;n++){
        int rt = wc*64 + n*16 + lrow;
        bf[n] = *(const short8*)(smB + rt*128 + ((kbb ^ (rt&7))<<4));
      }
      #pragma unroll
      for (int m=0;m<4;m++){
        #pragma unroll
        for (int n=0;n<4;n++)
          acc[m][n] = __builtin_amdgcn_mfma_f32_16x16x32_bf16(af[m], bf[n], acc[m][n], 0,0,0);
      }
    }
  }
  int tcol = col0 + wc*64;
  int type = tcol >> 9;           // 0=q, 1=k, 2=v
  int hd = (tcol >> 6) & 7;
  float al = alpha[hd];
  #pragma unroll
  for (int m=0;m<4;m++){
    #pragma unroll
    for (int j=0;j<4;j++){
      int row = row0 + wr*64 + m*16 + lg*4 + j;
      float v4[4]; float ss = 0.f;
      #pragma unroll
      for (int n=0;n<4;n++){
        v4[n] = acc[m][n][j] + bias[tcol + n*16 + lrow];
        ss += v4[n]*v4[n];
      }
      ss += __shfl_xor(ss,1); ss += __shfl_xor(ss,2);
      ss += __shfl_xor(ss,4); ss += __shfl_xor(ss,8);
      int b = row >> 10, tt = row & 1023;
      size_t hb = ((size_t)(b*8+hd))*65536;
      if (type == 0){
        float sc = al / (sqrtf(ss) + 1e-5f);
        #pragma unroll
        for (int n=0;n<4;n++)
          oq[hb + (size_t)tt*64 + n*16 + lrow] = f2bf(v4[n]*sc);
      } else if (type == 1){
        float sc = 1.f / (sqrtf(ss) + 1e-5f);
        #pragma unroll
        for (int n=0;n<4;n++)
          ok[hb + (size_t)tt*64 + n*16 + lrow] = f2bf(v4[n]*sc);
      } else {
        #pragma unroll
        for (int n=0;n<4;n++)
          ov[((size_t)(b*8+hd)*64 + n*16 + lrow)*1024 + tt] = f2bf(v4[n]);
      }
    }
  }
}

// ---------------------------------------------------------------------------
// Legacy 128x128 GEMM for the small proj matmul: +resid, fp32+bf16 out
__global__ __launch_bounds__(256)
void gemm_proj(const unsigned short* __restrict__ A, const unsigned short* __restrict__ B,
               const float* __restrict__ bias,
               float* __restrict__ Cf, unsigned short* __restrict__ Ch,
               const float* __restrict__ resid, int M, int N, int K)
{
  __shared__ char smem[32768];
  char* smA = smem; char* smB = smem + 16384;
  int row0 = blockIdx.y * 128;
  int col0 = blockIdx.x * 128;
  int t = threadIdx.x, w = t>>6, lane = t&63;
  int lrow = lane&15, lg = lane>>4;
  int wr = w>>1, wc = w&1;

  f32x4 acc[4][4];
  #pragma unroll
  for (int i=0;i<4;i++){
    #pragma unroll
    for (int j=0;j<4;j++) acc[i][j] = f32x4{0.f,0.f,0.f,0.f};
  }
  const size_t Abase = (size_t)row0 * K;
  const size_t Bbase = (size_t)col0 * K;
  int nkt = K >> 6;
  for (int kt=0; kt<nkt; kt++){
    __syncthreads();
    int k0 = kt*64;
    #pragma unroll
    for (int i=0;i<4;i++){
      int s = (i*4 + w)*64 + lane;
      int r = s>>3;
      int kb = (s&7) ^ (r&7);
      gload_lds16(A + Abase + (size_t)r*K + k0 + kb*8, smA + (size_t)(i*4+w)*1024);
      gload_lds16(B + Bbase + (size_t)r*K + k0 + kb*8, smB + (size_t)(i*4+w)*1024);
    }
    __syncthreads();
    #pragma unroll
    for (int ks=0; ks<2; ks++){
      short8 af[4], bf[4];
      int kbb = lg + ks*4;
      #pragma unroll
      for (int m=0;m<4;m++){
        int rt = wr*64 + m*16 + lrow;
        af[m] = *(const short8*)(smA + rt*128 + ((kbb ^ (rt&7))<<4));
      }
      #pragma unroll
      for (int n=0;n<4;n++){
        int rt = wc*64 + n*16 + lrow;
        bf[n] = *(const short8*)(smB + rt*128 + ((kbb ^ (rt&7))<<4));
      }
      #pragma unroll
      for (int m=0;m<4;m++){
        #pragma unroll
        for (int n=0;n<4;n++)
          acc[m][n] = __builtin_amdgcn_mfma_f32_16x16x32_bf16(af[m], bf[n], acc[m][n], 0,0,0);
      }
    }
  }
  #pragma unroll
  for (int m=0;m<4;m++){
    int rloc = wr*64 + m*16 + lg*4;
    #pragma unroll
    for (int j=0;j<4;j++){
      int row = row0 + rloc + j;
      size_t rg = (size_t)row;
      #pragma unroll
      for (int n=0;n<4;n++){
        int col = col0 + wc*64 + n*16 + lrow;
        float v = acc[m][n][j] + bias[col];
        size_t idx = rg * N + col;
        v += resid[idx];
        Cf[idx] = v;
        Ch[idx] = f2bf(v);
      }
    }
  }
}

// ---------------------------------------------------------------------------
// Flash attention, 64-row q-tiles (grid 16x16 = 256 blocks).
__global__ __launch_bounds__(256)
void attn_k(const unsigned short* __restrict__ q_s, const unsigned short* __restrict__ k_hat,
            const unsigned short* __restrict__ v_t, unsigned short* __restrict__ y)
{
  __shared__ char sm[51200];
  char* smK = sm + 18432;
  char* smV = sm + 34816;
  int qt = blockIdx.x, bh = blockIdx.y;
  int b = bh>>3, h = bh&7;
  int t = threadIdx.x, w = t>>6, lane = t&63;
  int lrow = lane&15, lg = lane>>4;
  int q0 = qt*64;
  const size_t hQK = (size_t)bh*1024*64;
  const size_t hV  = (size_t)bh*64*1024;

  #pragma unroll
  for (int i=0;i<2;i++){
    int si = i*256 + t;
    int r = si>>3, kb = (si&7)^(r&7);
    gload_lds16(q_s + hQK + (size_t)(q0+r)*64 + kb*8, sm + (size_t)si*16);
  }
  __syncthreads();
  short8 qf[2];
  #pragma unroll
  for (int ks=0;ks<2;ks++){
    int rt = w*16 + lrow;
    int kbb = lg + ks*4;
    qf[ks] = *(const short8*)(sm + rt*128 + ((kbb^(rt&7))<<4));
  }
  f32x4 oacc[4];
  #pragma unroll
  for (int j=0;j<4;j++) oacc[j] = f32x4{0.f,0.f,0.f,0.f};
  float mrun[4], lrun[4];
  #pragma unroll
  for (int j=0;j<4;j++){ mrun[j] = -1e30f; lrun[j] = 0.f; }
  char* Pw = sm + w*2304;

  int ktmax = (q0 + 63) >> 7;
  for (int kt=0; kt<=ktmax; kt++){
    __syncthreads();
    int t0 = kt*128;
    #pragma unroll
    for (int i=0;i<4;i++){
      int s = (i*4+w)*64 + lane;
      int r = s>>3, kb = (s&7)^(r&7);
      gload_lds16(k_hat + hQK + (size_t)(t0+r)*64 + kb*8, smK + (size_t)(i*4+w)*1024);
    }
    #pragma unroll
    for (int i=0;i<4;i++){
      int s = (i*4+w)*64 + lane;
      int d = s>>4, kb2 = s&15;
      int kb = kb2 ^ (d&7);
      gload_lds16(v_t + hV + (size_t)d*1024 + t0 + kb*8, smV + (size_t)(i*4+w)*1024);
    }
    __syncthreads();

    f32x4 sacc[8];
    #pragma unroll
    for (int j=0;j<8;j++) sacc[j] = f32x4{0.f,0.f,0.f,0.f};
    #pragma unroll
    for (int ks=0;ks<2;ks++){
      short8 kf[8];
      int kbb = lg + ks*4;
      #pragma unroll
      for (int nf=0;nf<8;nf++){
        int rt = nf*16+lrow;
        kf[nf] = *(const short8*)(smK + rt*128 + ((kbb^(rt&7))<<4));
      }
      #pragma unroll
      for (int nf=0;nf<8;nf++)
        sacc[nf] = __builtin_amdgcn_mfma_f32_16x16x32_bf16(qf[ks], kf[nf], sacc[nf], 0,0,0);
    }
    if (kt == ktmax){
      #pragma unroll
      for (int nf=0;nf<8;nf++){
        #pragma unroll
        for (int j=0;j<4;j++){
          int qi = q0 + w*16 + lg*4 + j;
          int ki = t0 + nf*16 + lrow;
          if (ki > qi) sacc[nf][j] = -1e30f;
        }
      }
    }
    #pragma unroll
    for (int j=0;j<4;j++){
      float mx = sacc[0][j];
      #pragma unroll
      for (int nf=1;nf<8;nf++) mx = fmaxf(mx, sacc[nf][j]);
      #pragma unroll
      for (int m=1;m<16;m<<=1) mx = fmaxf(mx, __shfl_xor(mx, m));
      float mnew = fmaxf(mrun[j], mx);
      float sc = __expf(mrun[j] - mnew);
      float rs = 0.f;
      #pragma unroll
      for (int nf=0;nf<8;nf++){
        float p = __expf(sacc[nf][j] - mnew);
        sacc[nf][j] = p; rs += p;
      }
      #pragma unroll
      for (int m=1;m<16;m<<=1) rs += __shfl_xor(rs, m);
      lrun[j] = lrun[j]*sc + rs;
      mrun[j] = mnew;
      #pragma unroll
      for (int n2=0;n2<4;n2++) oacc[n2][j] *= sc;
    }
    #pragma unroll
    for (int half=0; half<2; half++){
      #pragma unroll
      for (int nfh=0;nfh<4;nfh++){
        int nf = half*4 + nfh;
        #pragma unroll
        for (int j=0;j<4;j++){
          int row = lg*4 + j;
          int col = nfh*16 + lrow;
          *(unsigned short*)(Pw + (row*72 + col)*2) = f2bf(sacc[nf][j]);
        }
      }
      #pragma unroll
      for (int k2=0;k2<2;k2++){
        int ks2 = half*2 + k2;
        short8 pf, vf[4];
        pf = *(const short8*)(Pw + lrow*144 + lg*16 + k2*64);
        #pragma unroll
        for (int n2=0;n2<4;n2++){
          int d = n2*16+lrow;
          int kbb2 = lg + ks2*4;
          vf[n2] = *(const short8*)(smV + d*256 + ((kbb2^(d&7))<<4));
        }
        #pragma unroll
        for (int n2=0;n2<4;n2++)
          oacc[n2] = __builtin_amdgcn_mfma_f32_16x16x32_bf16(pf, vf[n2], oacc[n2], 0,0,0);
      }
    }
  }
  #pragma unroll
  for (int n2=0;n2<4;n2++){
    #pragma unroll
    for (int j=0;j<4;j++){
      float v = oacc[n2][j] / lrun[j];
      int qi = q0 + w*16 + lg*4 + j;
      int d = n2*16 + lrow;
      y[((size_t)(b*1024+qi))*512 + h*64 + d] = f2bf(v);
    }
  }
}

// ---------------------------------------------------------------------------
__global__ __launch_bounds__(256)
void router_topk(const float* __restrict__ x2f, const float* __restrict__ rw,
                 const float* __restrict__ rb, float* __restrict__ gates)
{
  int tkn = blockIdx.x*4 + (threadIdx.x>>6);
  int lane = threadIdx.x & 63;
  int e = lane & 15, p = lane >> 4;
  const float* xr = x2f + (size_t)tkn*512;
  float part = 0.f;
  for (int d = p*128; d < p*128+128; d++)
    part += xr[d] * rw[d*16 + e];
  part += __shfl_xor(part, 16);
  part += __shfl_xor(part, 32);
  float logit = part + rb[e];
  float mx = logit;
  #pragma unroll
  for (int m=1;m<16;m<<=1) mx = fmaxf(mx, __shfl_xor(mx, m));
  float ex = __expf(logit - mx);
  float sm = ex;
  #pragma unroll
  for (int m=1;m<16;m<<=1) sm += __shfl_xor(sm, m);
  float prob = ex / sm;
  bool taken = false;
  float ssum = 0.f;
  #pragma unroll
  for (int r=0;r<8;r++){
    float cv = taken ? -1.f : prob;
    int ci = e;
    #pragma unroll
    for (int m=1;m<16;m<<=1){
      float ov = __shfl_xor(cv, m);
      int oi = __shfl_xor(ci, m);
      if (ov > cv || (ov == cv && oi < ci)){ cv = ov; ci = oi; }
    }
    if (e == ci) taken = true;
    ssum += cv;
  }
  if (lane < 16)
    gates[(size_t)tkn*16 + e] = taken ? prob / ssum : 0.f;
}

// ---------------------------------------------------------------------------
__global__ void listbuild(const float* __restrict__ gates, int* __restrict__ list,
                          int* __restrict__ slot, int* __restrict__ cnt)
{
  int e = blockIdx.x;
  int tid = threadIdx.x, w = tid>>6, lane = tid&63;
  __shared__ int sbase;
  __shared__ int wsum[4];
  if (tid==0) sbase = 0;
  __syncthreads();
  for (int c=0;c<8;c++){
    int tk = c*256 + tid;
    bool flag = gates[(size_t)tk*16 + e] > 0.f;
    unsigned long long bal = __ballot(flag);
    if (lane==0) wsum[w] = (int)__popcll(bal);
    __syncthreads();
    int wpref = 0;
    for (int i=0;i<w;i++) wpref += wsum[i];
    int tot = wsum[0]+wsum[1]+wsum[2]+wsum[3];
    int lpref = (int)__popcll(bal & ((1ull<<lane)-1ull));
    if (flag){
      int pos = sbase + wpref + lpref;
      list[e*2048 + pos] = tk;
      slot[(size_t)tk*16 + e] = pos;
    }
    __syncthreads();
    if (tid==0) sbase += tot;
    __syncthreads();
  }
  if (tid==0) cnt[e] = sbase;
}

__global__ void prefix_off(const int* __restrict__ cnt, int* __restrict__ off){
  if (threadIdx.x==0 && blockIdx.x==0){
    int a=0;
    for (int e=0;e<16;e++){ off[e]=a; a+=cnt[e]; }
    off[16]=a;
  }
}

__global__ __launch_bounds__(256)
void gather_rows(const unsigned short* __restrict__ x2h, const int* __restrict__ list,
                 const int* __restrict__ cnt, const int* __restrict__ off,
                 unsigned short* __restrict__ xe)
{
  int e = blockIdx.y;
  int s = blockIdx.x*4 + (threadIdx.x>>6);
  if (s >= cnt[e]) return;
  int lane = threadIdx.x & 63;
  int tk = list[e*2048 + s];
  *(short8*)(xe + ((size_t)(off[e]+s))*512 + lane*8) =
      *(const short8*)(x2h + (size_t)tk*512 + lane*8);
}

__global__ __launch_bounds__(256)
void combine_k(const float* __restrict__ x2f, const unsigned short* __restrict__ eo,
               const float* __restrict__ gates, const int* __restrict__ slot,
               const int* __restrict__ off, float* __restrict__ out)
{
  int tkn = blockIdx.x;
  __shared__ float gs[16];
  __shared__ int rws[16];
  int tid = threadIdx.x;
  if (tid < 16){
    float g = gates[(size_t)tkn*16 + tid];
    gs[tid] = g;
    rws[tid] = (g > 0.f) ? (off[tid] + slot[(size_t)tkn*16 + tid]) : 0;
  }
  __syncthreads();
  for (int d = tid; d < 512; d += 256){
    float v = x2f[(size_t)tkn*512 + d];
    #pragma unroll
    for (int e=0;e<16;e++){
      float g = gs[e];
      if (g > 0.f) v += g * bf2f(eo[(size_t)rws[e]*512 + d]);
    }
    out[(size_t)tkn*512 + d] = v;
  }
}

// ---------------------------------------------------------------------------
extern "C" void kernel_launch(void* const* d_in, const int* in_sizes, int n_in,
                              void* d_out, int out_size, void* d_ws, size_t ws_size,
                              hipStream_t stream) {
  (void)in_sizes; (void)n_in; (void)out_size; (void)ws_size;
  const float* x    = (const float*)d_in[0];
  const float* gw   = (const float*)d_in[1];
  const float* bw   = (const float*)d_in[2];
  const float* caw  = (const float*)d_in[3];
  const float* cab  = (const float*)d_in[4];
  const float* alpha= (const float*)d_in[5];
  const float* cpw  = (const float*)d_in[6];
  const float* cpb  = (const float*)d_in[7];
  const float* rw   = (const float*)d_in[8];
  const float* rb   = (const float*)d_in[9];
  const float* w_in = (const float*)d_in[10];
  const float* b_in = (const float*)d_in[11];
  const float* w1   = (const float*)d_in[12];
  const float* b1   = (const float*)d_in[13];
  const float* w2   = (const float*)d_in[14];
  const float* b2   = (const float*)d_in[15];
  const float* w_out= (const float*)d_in[16];
  const float* b_out= (const float*)d_in[17];

  char* ws = (char*)d_ws;
  size_t o = 0;
  auto alloc = [&](size_t bytes)->char*{
    char* p = ws + o;
    o += (bytes + 255) & ~(size_t)255;
    return p;
  };
  const size_t PADROWS = 16896;  // 16384 + tile overread pad
  unsigned short* wT_attn = (unsigned short*)alloc(1536ull*512*2);
  unsigned short* wT_proj = (unsigned short*)alloc(512ull*512*2);
  unsigned short* wT_in   = (unsigned short*)alloc(16ull*2048*512*2);
  unsigned short* wT1p    = (unsigned short*)alloc(16ull*4096*2048*2);
  unsigned short* wT_2    = (unsigned short*)alloc(16ull*2048*2048*2);
  unsigned short* wT_out  = (unsigned short*)alloc(16ull*512*2048*2);
  unsigned short* xn      = (unsigned short*)alloc(2048ull*512*2);
  unsigned short* q_s     = (unsigned short*)alloc(2048ull*512*2);
  unsigned short* k_hat   = (unsigned short*)alloc(2048ull*512*2);
  unsigned short* v_t     = (unsigned short*)alloc(2048ull*512*2);
  unsigned short* ybuf    = (unsigned short*)alloc(2048ull*512*2);
  float*          x2f     = (float*)alloc(2048ull*512*4);
  unsigned short* x2h     = (unsigned short*)alloc(2048ull*512*2);
  float*          gates   = (float*)alloc(2048ull*16*4);
  int*            slot    = (int*)alloc(2048ull*16*4);
  int*            list    = (int*)alloc(16ull*2048*4);
  int*            cnt     = (int*)alloc(64);
  int*            off     = (int*)alloc(256);
  unsigned short* xe      = (unsigned short*)alloc(PADROWS*512*2);   // + eo alias
  unsigned short* hbuf    = (unsigned short*)alloc(PADROWS*2048*2);  // + o alias
  unsigned short* sbuf    = (unsigned short*)alloc(PADROWS*2048*2);
  unsigned short* eobuf   = xe;   // xe dead after h-GEMM
  unsigned short* obuf    = hbuf; // hbuf dead after fused SwiGLU GEMM

  dim3 blk(256);
  // one merged prep dispatch (8-tile blocks): weight transposes + rmsnorm
  prep_all<<<29312, blk, 0, stream>>>(caw, cpw, w_in, w1, w2, w_out,
                                      wT_attn, wT_proj, wT_in, wT1p, wT_2, wT_out,
                                      x, gw, bw, xn);

  // qkv GEMM (128^2, 192 blocks) with fused head-norm epilogue
  gemm_qkv<<<dim3(12, 16), blk, 0, stream>>>(xn, wT_attn, cab, alpha,
                                             q_s, k_hat, v_t, 1536, 512);
  attn_k<<<dim3(16,16), blk, 0, stream>>>(q_s, k_hat, v_t, ybuf);
  gemm_proj<<<dim3(4,16,1), blk, 0, stream>>>(ybuf, wT_proj, cpb, x2f, x2h, x, 2048, 512, 512);
  router_topk<<<512, blk, 0, stream>>>(x2f, rw, rb, gates);
  listbuild<<<16, blk, 0, stream>>>(gates, list, slot, cnt);
  prefix_off<<<1, 64, 0, stream>>>(cnt, off);
  gather_rows<<<dim3(512,16), blk, 0, stream>>>(x2h, list, cnt, off, xe);

  // experts: 128^2 high-occupancy engine (batched over z, compacted via off[])
  gemmE<1><<<dim3(16,16,16), blk, 0, stream>>>(xe, wT_in, b_in, hbuf,
                                               2048, 512, off, 2048ll*512, 2048);
  gemmE<2><<<dim3(32,16,16), blk, 0, stream>>>(hbuf, wT1p, b1, sbuf,
                                               4096, 2048, off, 4096ll*2048, 4096);
  gemmE<1><<<dim3(16,16,16), blk, 0, stream>>>(sbuf, wT_2, b2, obuf,
                                               2048, 2048, off, 2048ll*2048, 2048);
  gemmE<1><<<dim3(4,16,16), blk, 0, stream>>>(obuf, wT_out, b_out, eobuf,
                                              512, 2048, off, 512ll*2048, 512);
  combine_k<<<2048, blk, 0, stream>>>(x2f, eobuf, gates, slot, off, (float*)d_out);
}

// Round 15
// 1002.044 us; speedup vs baseline: 1.0535x; 1.0535x over previous
//
#include <hip/hip_runtime.h>
#include <stdint.h>

#define DEVI __device__ __forceinline__
#define FENCE() asm volatile("" ::: "memory")
#define BAR() do{ FENCE(); __builtin_amdgcn_s_barrier(); FENCE(); }while(0)

typedef short short8 __attribute__((ext_vector_type(8)));
typedef short short4v __attribute__((ext_vector_type(4)));
typedef float f32x4 __attribute__((ext_vector_type(4)));

DEVI float bf2f(unsigned short s){ union{unsigned u; float f;} x; x.u = ((unsigned)s)<<16; return x.f; }
DEVI unsigned short f2bf(float f){ union{float f; unsigned u;} x; x.f=f; unsigned r = x.u + 0x7fff + ((x.u>>16)&1); return (unsigned short)(r>>16); }

DEVI void gload_lds16(const void* g, void* l){
  __builtin_amdgcn_global_load_lds((const __attribute__((address_space(1))) unsigned int*)g,
                                   (__attribute__((address_space(3))) unsigned int*)l, 16, 0, 0);
}

// ---------------------------------------------------------------------------
// Merged weight-prep kernel, 8-tile blocks for 8x memory-level parallelism.
__global__ __launch_bounds__(256)
void prep_all(const float* __restrict__ caw, const float* __restrict__ cpw,
              const float* __restrict__ w_in, const float* __restrict__ w1,
              const float* __restrict__ w2, const float* __restrict__ w_out,
              unsigned short* __restrict__ wT_attn, unsigned short* __restrict__ wT_proj,
              unsigned short* __restrict__ wT_in, unsigned short* __restrict__ wT1p,
              unsigned short* __restrict__ wT_2, unsigned short* __restrict__ wT_out,
              const float* __restrict__ x, const float* __restrict__ gw,
              const float* __restrict__ bw, unsigned short* __restrict__ xn)
{
  __shared__ float tile[8][32][33];
  int bid = blockIdx.x;
  int t = threadIdx.x;
  int tr = t>>3, tc = (t&7)*4;

  const float* src = nullptr; unsigned short* dst = nullptr;
  int K=0, N=0, kb=0, nb0=0;

  if (bid < 96){                     // attn W: K=512,N=1536, nx8=6, ny=16
    int xb8 = bid % 6, yb = bid / 6;
    src = caw; dst = wT_attn; K=512; N=1536; kb=yb*32; nb0=xb8*256;
  } else if ((bid -= 96) < 32){      // proj: 512x512, nx8=2, ny=16
    int xb8 = bid % 2, yb = bid / 2;
    src = cpw; dst = wT_proj; K=512; N=512; kb=yb*32; nb0=xb8*256;
  } else if ((bid -= 32) < 2048){    // w_in: K=512,N=2048, nx8=8, ny=16, z=16
    int z = bid >> 7, r = bid & 127;
    int xb8 = r % 8, yb = r / 8;
    src = w_in + (size_t)z*512*2048; dst = wT_in + (size_t)z*2048*512;
    K=512; N=2048; kb=yb*32; nb0=xb8*256;
  } else if ((bid -= 2048) < 16384){ // w1 permuted: nx8=16, ny=64, z=16
    int z = bid >> 10, r = bid & 1023;
    int xb8 = r % 16, yb = r / 16;
    const float* s1 = w1 + (size_t)z*2048*4096;
    unsigned short* d1 = wT1p + (size_t)z*4096*2048;
    int k0 = yb*32;
    float4 v[8];
    #pragma unroll
    for (int j=0;j<8;j++){
      int g = xb8*8 + j;
      int srccol = (tc < 16) ? (g*16 + tc) : (2048 + g*16 + (tc-16));
      v[j] = *(const float4*)(s1 + (size_t)(k0+tr)*4096 + srccol);
    }
    #pragma unroll
    for (int j=0;j<8;j++){
      tile[j][tr][tc+0]=v[j].x; tile[j][tr][tc+1]=v[j].y;
      tile[j][tr][tc+2]=v[j].z; tile[j][tr][tc+3]=v[j].w;
    }
    __syncthreads();
    #pragma unroll
    for (int j=0;j<8;j++){
      int np0 = xb8*256 + 32*j;
      short4v ov;
      ov[0] = (short)f2bf(tile[j][tc+0][tr]);
      ov[1] = (short)f2bf(tile[j][tc+1][tr]);
      ov[2] = (short)f2bf(tile[j][tc+2][tr]);
      ov[3] = (short)f2bf(tile[j][tc+3][tr]);
      *(short4v*)(d1 + (size_t)(np0+tr)*2048 + k0 + tc) = ov;
    }
    return;
  } else if ((bid -= 16384) < 8192){ // w2: 2048x2048, nx8=8, ny=64, z=16
    int z = bid >> 9, r = bid & 511;
    int xb8 = r % 8, yb = r / 8;
    src = w2 + (size_t)z*2048*2048; dst = wT_2 + (size_t)z*2048*2048;
    K=2048; N=2048; kb=yb*32; nb0=xb8*256;
  } else if ((bid -= 8192) < 2048){  // w_out: K=2048,N=512, nx8=2, ny=64, z=16
    int z = bid >> 7, r = bid & 127;
    int xb8 = r % 2, yb = r / 2;
    src = w_out + (size_t)z*2048*512; dst = wT_out + (size_t)z*512*2048;
    K=2048; N=512; kb=yb*32; nb0=xb8*256;
  } else {                           // rmsnorm: 512 blocks x 4 rows
    bid -= 2048;
    int row = bid*4 + (t>>6);
    int lane = t & 63;
    const float* xr = x + (size_t)row*512 + lane*8;
    float4 a = *(const float4*)xr;
    float4 c = *(const float4*)(xr+4);
    float ss = a.x*a.x+a.y*a.y+a.z*a.z+a.w*a.w + c.x*c.x+c.y*c.y+c.z*c.z+c.w*c.w;
    #pragma unroll
    for (int m=1;m<64;m<<=1) ss += __shfl_xor(ss, m);
    float inv = 1.0f / sqrtf(ss*(1.f/512.f) + 1e-6f);
    const float* gr = gw + lane*8; const float* br = bw + lane*8;
    float4 g0=*(const float4*)gr, g1=*(const float4*)(gr+4);
    float4 b0=*(const float4*)br, b1=*(const float4*)(br+4);
    short8 o;
    o[0]=(short)f2bf(a.x*inv*g0.x + b0.x);
    o[1]=(short)f2bf(a.y*inv*g0.y + b0.y);
    o[2]=(short)f2bf(a.z*inv*g0.z + b0.z);
    o[3]=(short)f2bf(a.w*inv*g0.w + b0.w);
    o[4]=(short)f2bf(c.x*inv*g1.x + b1.x);
    o[5]=(short)f2bf(c.y*inv*g1.y + b1.y);
    o[6]=(short)f2bf(c.z*inv*g1.z + b1.z);
    o[7]=(short)f2bf(c.w*inv*g1.w + b1.w);
    *(short8*)(xn + (size_t)row*512 + lane*8) = o;
    return;
  }
  {
    float4 v[8];
    #pragma unroll
    for (int j=0;j<8;j++)
      v[j] = *(const float4*)(src + (size_t)(kb+tr)*N + nb0 + 32*j + tc);
    #pragma unroll
    for (int j=0;j<8;j++){
      tile[j][tr][tc+0]=v[j].x; tile[j][tr][tc+1]=v[j].y;
      tile[j][tr][tc+2]=v[j].z; tile[j][tr][tc+3]=v[j].w;
    }
    __syncthreads();
    #pragma unroll
    for (int j=0;j<8;j++){
      short4v ov;
      ov[0] = (short)f2bf(tile[j][tc+0][tr]);
      ov[1] = (short)f2bf(tile[j][tc+1][tr]);
      ov[2] = (short)f2bf(tile[j][tc+2][tr]);
      ov[3] = (short)f2bf(tile[j][tc+3][tr]);
      *(short4v*)(dst + (size_t)(nb0+32*j+tr)*K + kb + tc) = ov;
    }
  }
}

// ---------------------------------------------------------------------------
// 256x256 pipelined GEMM, 4 phases/K-tile (proven engine; experts only).
// EPI: 1 = bf16 out + bias; 2 = fused SwiGLU (permuted W1, N=4096 acc ->
//      2048-col bf16 out; bias[0..2047]=a, [2048..4095]=gate)
#define READ_AFR(Q) do{ \
  _Pragma("unroll") \
  for (int m2=0;m2<2;m2++){ \
    int rt = wm*128 + ((Q)*2+m2)*16 + lrow; \
    _Pragma("unroll") \
    for (int kk=0;kk<2;kk++) \
      afr[m2][kk] = *(const short8*)(sA + rt*128 + (((lg+kk*4)^(rt&7))<<4)); \
  } \
}while(0)

#define QUADP(Q) do{ \
  __builtin_amdgcn_s_setprio(1); \
  _Pragma("unroll") \
  for (int m2=0;m2<2;m2++){ \
    _Pragma("unroll") \
    for (int n=0;n<4;n++){ \
      _Pragma("unroll") \
      for (int kk=0;kk<2;kk++) \
        acc[(Q)*2+m2][n] = __builtin_amdgcn_mfma_f32_16x16x32_bf16(afr[m2][kk], bfr[n][kk], acc[(Q)*2+m2][n], 0,0,0); \
    } \
  } \
  __builtin_amdgcn_s_setprio(0); \
}while(0)

template<int EPI>
__global__ __launch_bounds__(512, 2)
void gemmT(const unsigned short* __restrict__ A, const unsigned short* __restrict__ B,
           const float* __restrict__ bias,
           unsigned short* __restrict__ Ch,
           int M, int N, int K,
           const int* __restrict__ off, long long strideBz, long long strideBiasz)
{
  __shared__ char smem[131072];
  int z = blockIdx.z;
  int rowbase = 0, Mz = M;
  if (off){ rowbase = off[z]; Mz = off[z+1] - rowbase; }
  int row0 = blockIdx.y * 256;
  if (row0 >= Mz) return;
  int col0 = blockIdx.x * 256;
  const unsigned short* Ab = A + (size_t)(rowbase + row0) * K;
  const unsigned short* Bb = B + (size_t)z * strideBz + (size_t)col0 * K;
  const float* biasz = bias + (size_t)z * strideBiasz;

  int tid = threadIdx.x;
  int lane = tid & 63, w = tid >> 6;
  int lrow = lane & 15, lg = lane >> 4;
  int wm = w >> 2, wn = w & 3;

  f32x4 acc[8][4];
  #pragma unroll
  for (int i=0;i<8;i++){
    #pragma unroll
    for (int j=0;j<4;j++) acc[i][j] = f32x4{0.f,0.f,0.f,0.f};
  }
  int nkt = K >> 6;
  auto stage = [&](int kt2, int H){
    if (kt2 >= nkt) return;
    char* sl = smem + (kt2 & 1) * 65536 + H * 16384;
    int k0 = kt2 << 6;
    const unsigned short* src = (H < 2) ? Ab : Bb;
    int rbase = (H & 1) * 128;
    #pragma unroll
    for (int i=0;i<2;i++){
      int si = i*512 + tid;
      int r = si >> 3, kb = (si & 7) ^ (r & 7);
      gload_lds16(src + (size_t)(rbase + r)*K + k0 + kb*8, sl + si*16);
    }
  };
  stage(0,0); stage(0,1); stage(0,2); stage(0,3);
  stage(1,2); stage(1,3);
  asm volatile("s_waitcnt vmcnt(4)" ::: "memory");
  BAR();
  for (int kt = 0; kt < nkt; kt++){
    char* sA = smem + (kt & 1) * 65536;
    char* sB = sA + 32768;
    short8 bfr[4][2], afr[2][2];
    #pragma unroll
    for (int n=0;n<4;n++){
      int ct = wn*64 + n*16 + lrow;
      #pragma unroll
      for (int kk=0;kk<2;kk++)
        bfr[n][kk] = *(const short8*)(sB + ct*128 + (((lg+kk*4)^(ct&7))<<4));
    }
    READ_AFR(0);
    stage(kt+1, 0); stage(kt+1, 1);
    BAR();
    QUADP(0);
    BAR();
    READ_AFR(1);
    stage(kt+2, 2);
    BAR();
    QUADP(1);
    BAR();
    READ_AFR(2);
    stage(kt+2, 3);
    BAR();
    QUADP(2);
    BAR();
    READ_AFR(3);
    if (kt + 2 < nkt) { asm volatile("s_waitcnt vmcnt(4)" ::: "memory"); }
    else              { asm volatile("s_waitcnt vmcnt(0)" ::: "memory"); }
    BAR();
    QUADP(3);
    BAR();
  }
  #pragma unroll
  for (int m=0;m<8;m++){
    #pragma unroll
    for (int j=0;j<4;j++){
      int row = row0 + wm*128 + m*16 + lg*4 + j;
      if (row < Mz){
        size_t rg = (size_t)(rowbase + row);
        if constexpr (EPI == 2){
          #pragma unroll
          for (int nf=0;nf<4;nf+=2){
            int pcol = col0 + wn*64 + nf*16;
            int scol = ((pcol>>5)<<4) + lrow;
            float av = acc[m][nf][j]   + biasz[scol];
            float gv = acc[m][nf+1][j] + biasz[2048 + scol];
            float sg = gv / (1.f + __expf(-gv));
            Ch[rg*2048 + scol] = f2bf(av * sg);
          }
        } else {
          #pragma unroll
          for (int n=0;n<4;n++){
            int col = col0 + wn*64 + n*16 + lrow;
            float v = acc[m][n][j] + biasz[col];
            Ch[rg * N + col] = f2bf(v);
          }
        }
      }
    }
  }
}

// ---------------------------------------------------------------------------
// 128x128 GEMM with fused qkv head-norm epilogue (192 blocks -> 75% GPU).
__global__ __launch_bounds__(256)
void gemm_qkv(const unsigned short* __restrict__ A, const unsigned short* __restrict__ B,
              const float* __restrict__ bias, const float* __restrict__ alpha,
              unsigned short* __restrict__ oq, unsigned short* __restrict__ ok,
              unsigned short* __restrict__ ov, int N, int K)
{
  __shared__ char smem[32768];
  char* smA = smem; char* smB = smem + 16384;
  int row0 = blockIdx.y * 128;
  int col0 = blockIdx.x * 128;
  int t = threadIdx.x, w = t>>6, lane = t&63;
  int lrow = lane&15, lg = lane>>4;
  int wr = w>>1, wc = w&1;

  f32x4 acc[4][4];
  #pragma unroll
  for (int i=0;i<4;i++){
    #pragma unroll
    for (int j=0;j<4;j++) acc[i][j] = f32x4{0.f,0.f,0.f,0.f};
  }
  const size_t Abase = (size_t)row0 * K;
  const size_t Bbase = (size_t)col0 * K;
  int nkt = K >> 6;
  for (int kt=0; kt<nkt; kt++){
    __syncthreads();
    int k0 = kt*64;
    #pragma unroll
    for (int i=0;i<4;i++){
      int s = (i*4 + w)*64 + lane;
      int r = s>>3;
      int kb = (s&7) ^ (r&7);
      gload_lds16(A + Abase + (size_t)r*K + k0 + kb*8, smA + (size_t)(i*4+w)*1024);
      gload_lds16(B + Bbase + (size_t)r*K + k0 + kb*8, smB + (size_t)(i*4+w)*1024);
    }
    __syncthreads();
    #pragma unroll
    for (int ks=0; ks<2; ks++){
      short8 af[4], bf[4];
      int kbb = lg + ks*4;
      #pragma unroll
      for (int m=0;m<4;m++){
        int rt = wr*64 + m*16 + lrow;
        af[m] = *(const short8*)(smA + rt*128 + ((kbb ^ (rt&7))<<4));
      }
      #pragma unroll
      for (int n=0;n<4;n++){
        int rt = wc*64 + n*16 + lrow;
        bf[n] = *(const short8*)(smB + rt*128 + ((kbb ^ (rt&7))<<4));
      }
      #pragma unroll
      for (int m=0;m<4;m++){
        #pragma unroll
        for (int n=0;n<4;n++)
          acc[m][n] = __builtin_amdgcn_mfma_f32_16x16x32_bf16(af[m], bf[n], acc[m][n], 0,0,0);
      }
    }
  }
  int tcol = col0 + wc*64;
  int type = tcol >> 9;           // 0=q, 1=k, 2=v
  int hd = (tcol >> 6) & 7;
  float al = alpha[hd];
  #pragma unroll
  for (int m=0;m<4;m++){
    #pragma unroll
    for (int j=0;j<4;j++){
      int row = row0 + wr*64 + m*16 + lg*4 + j;
      float v4[4]; float ss = 0.f;
      #pragma unroll
      for (int n=0;n<4;n++){
        v4[n] = acc[m][n][j] + bias[tcol + n*16 + lrow];
        ss += v4[n]*v4[n];
      }
      ss += __shfl_xor(ss,1); ss += __shfl_xor(ss,2);
      ss += __shfl_xor(ss,4); ss += __shfl_xor(ss,8);
      int b = row >> 10, tt = row & 1023;
      size_t hb = ((size_t)(b*8+hd))*65536;
      if (type == 0){
        float sc = al / (sqrtf(ss) + 1e-5f);
        #pragma unroll
        for (int n=0;n<4;n++)
          oq[hb + (size_t)tt*64 + n*16 + lrow] = f2bf(v4[n]*sc);
      } else if (type == 1){
        float sc = 1.f / (sqrtf(ss) + 1e-5f);
        #pragma unroll
        for (int n=0;n<4;n++)
          ok[hb + (size_t)tt*64 + n*16 + lrow] = f2bf(v4[n]*sc);
      } else {
        #pragma unroll
        for (int n=0;n<4;n++)
          ov[((size_t)(b*8+hd)*64 + n*16 + lrow)*1024 + tt] = f2bf(v4[n]);
      }
    }
  }
}

// ---------------------------------------------------------------------------
// Legacy 128x128 GEMM for the small proj matmul: +resid, fp32+bf16 out
__global__ __launch_bounds__(256)
void gemm_proj(const unsigned short* __restrict__ A, const unsigned short* __restrict__ B,
               const float* __restrict__ bias,
               float* __restrict__ Cf, unsigned short* __restrict__ Ch,
               const float* __restrict__ resid, int M, int N, int K)
{
  __shared__ char smem[32768];
  char* smA = smem; char* smB = smem + 16384;
  int row0 = blockIdx.y * 128;
  int col0 = blockIdx.x * 128;
  int t = threadIdx.x, w = t>>6, lane = t&63;
  int lrow = lane&15, lg = lane>>4;
  int wr = w>>1, wc = w&1;

  f32x4 acc[4][4];
  #pragma unroll
  for (int i=0;i<4;i++){
    #pragma unroll
    for (int j=0;j<4;j++) acc[i][j] = f32x4{0.f,0.f,0.f,0.f};
  }
  const size_t Abase = (size_t)row0 * K;
  const size_t Bbase = (size_t)col0 * K;
  int nkt = K >> 6;
  for (int kt=0; kt<nkt; kt++){
    __syncthreads();
    int k0 = kt*64;
    #pragma unroll
    for (int i=0;i<4;i++){
      int s = (i*4 + w)*64 + lane;
      int r = s>>3;
      int kb = (s&7) ^ (r&7);
      gload_lds16(A + Abase + (size_t)r*K + k0 + kb*8, smA + (size_t)(i*4+w)*1024);
      gload_lds16(B + Bbase + (size_t)r*K + k0 + kb*8, smB + (size_t)(i*4+w)*1024);
    }
    __syncthreads();
    #pragma unroll
    for (int ks=0; ks<2; ks++){
      short8 af[4], bf[4];
      int kbb = lg + ks*4;
      #pragma unroll
      for (int m=0;m<4;m++){
        int rt = wr*64 + m*16 + lrow;
        af[m] = *(const short8*)(smA + rt*128 + ((kbb ^ (rt&7))<<4));
      }
      #pragma unroll
      for (int n=0;n<4;n++){
        int rt = wc*64 + n*16 + lrow;
        bf[n] = *(const short8*)(smB + rt*128 + ((kbb ^ (rt&7))<<4));
      }
      #pragma unroll
      for (int m=0;m<4;m++){
        #pragma unroll
        for (int n=0;n<4;n++)
          acc[m][n] = __builtin_amdgcn_mfma_f32_16x16x32_bf16(af[m], bf[n], acc[m][n], 0,0,0);
      }
    }
  }
  #pragma unroll
  for (int m=0;m<4;m++){
    int rloc = wr*64 + m*16 + lg*4;
    #pragma unroll
    for (int j=0;j<4;j++){
      int row = row0 + rloc + j;
      size_t rg = (size_t)row;
      #pragma unroll
      for (int n=0;n<4;n++){
        int col = col0 + wc*64 + n*16 + lrow;
        float v = acc[m][n][j] + bias[col];
        size_t idx = rg * N + col;
        v += resid[idx];
        Cf[idx] = v;
        Ch[idx] = f2bf(v);
      }
    }
  }
}

// ---------------------------------------------------------------------------
// Flash attention, 64-row q-tiles (grid 16x16 = 256 blocks).
__global__ __launch_bounds__(256)
void attn_k(const unsigned short* __restrict__ q_s, const unsigned short* __restrict__ k_hat,
            const unsigned short* __restrict__ v_t, unsigned short* __restrict__ y)
{
  __shared__ char sm[51200];
  char* smK = sm + 18432;
  char* smV = sm + 34816;
  int qt = blockIdx.x, bh = blockIdx.y;
  int b = bh>>3, h = bh&7;
  int t = threadIdx.x, w = t>>6, lane = t&63;
  int lrow = lane&15, lg = lane>>4;
  int q0 = qt*64;
  const size_t hQK = (size_t)bh*1024*64;
  const size_t hV  = (size_t)bh*64*1024;

  #pragma unroll
  for (int i=0;i<2;i++){
    int si = i*256 + t;
    int r = si>>3, kb = (si&7)^(r&7);
    gload_lds16(q_s + hQK + (size_t)(q0+r)*64 + kb*8, sm + (size_t)si*16);
  }
  __syncthreads();
  short8 qf[2];
  #pragma unroll
  for (int ks=0;ks<2;ks++){
    int rt = w*16 + lrow;
    int kbb = lg + ks*4;
    qf[ks] = *(const short8*)(sm + rt*128 + ((kbb^(rt&7))<<4));
  }
  f32x4 oacc[4];
  #pragma unroll
  for (int j=0;j<4;j++) oacc[j] = f32x4{0.f,0.f,0.f,0.f};
  float mrun[4], lrun[4];
  #pragma unroll
  for (int j=0;j<4;j++){ mrun[j] = -1e30f; lrun[j] = 0.f; }
  char* Pw = sm + w*2304;

  int ktmax = (q0 + 63) >> 7;
  for (int kt=0; kt<=ktmax; kt++){
    __syncthreads();
    int t0 = kt*128;
    #pragma unroll
    for (int i=0;i<4;i++){
      int s = (i*4+w)*64 + lane;
      int r = s>>3, kb = (s&7)^(r&7);
      gload_lds16(k_hat + hQK + (size_t)(t0+r)*64 + kb*8, smK + (size_t)(i*4+w)*1024);
    }
    #pragma unroll
    for (int i=0;i<4;i++){
      int s = (i*4+w)*64 + lane;
      int d = s>>4, kb2 = s&15;
      int kb = kb2 ^ (d&7);
      gload_lds16(v_t + hV + (size_t)d*1024 + t0 + kb*8, smV + (size_t)(i*4+w)*1024);
    }
    __syncthreads();

    f32x4 sacc[8];
    #pragma unroll
    for (int j=0;j<8;j++) sacc[j] = f32x4{0.f,0.f,0.f,0.f};
    #pragma unroll
    for (int ks=0;ks<2;ks++){
      short8 kf[8];
      int kbb = lg + ks*4;
      #pragma unroll
      for (int nf=0;nf<8;nf++){
        int rt = nf*16+lrow;
        kf[nf] = *(const short8*)(smK + rt*128 + ((kbb^(rt&7))<<4));
      }
      #pragma unroll
      for (int nf=0;nf<8;nf++)
        sacc[nf] = __builtin_amdgcn_mfma_f32_16x16x32_bf16(qf[ks], kf[nf], sacc[nf], 0,0,0);
    }
    if (kt == ktmax){
      #pragma unroll
      for (int nf=0;nf<8;nf++){
        #pragma unroll
        for (int j=0;j<4;j++){
          int qi = q0 + w*16 + lg*4 + j;
          int ki = t0 + nf*16 + lrow;
          if (ki > qi) sacc[nf][j] = -1e30f;
        }
      }
    }
    #pragma unroll
    for (int j=0;j<4;j++){
      float mx = sacc[0][j];
      #pragma unroll
      for (int nf=1;nf<8;nf++) mx = fmaxf(mx, sacc[nf][j]);
      #pragma unroll
      for (int m=1;m<16;m<<=1) mx = fmaxf(mx, __shfl_xor(mx, m));
      float mnew = fmaxf(mrun[j], mx);
      float sc = __expf(mrun[j] - mnew);
      float rs = 0.f;
      #pragma unroll
      for (int nf=0;nf<8;nf++){
        float p = __expf(sacc[nf][j] - mnew);
        sacc[nf][j] = p; rs += p;
      }
      #pragma unroll
      for (int m=1;m<16;m<<=1) rs += __shfl_xor(rs, m);
      lrun[j] = lrun[j]*sc + rs;
      mrun[j] = mnew;
      #pragma unroll
      for (int n2=0;n2<4;n2++) oacc[n2][j] *= sc;
    }
    #pragma unroll
    for (int half=0; half<2; half++){
      #pragma unroll
      for (int nfh=0;nfh<4;nfh++){
        int nf = half*4 + nfh;
        #pragma unroll
        for (int j=0;j<4;j++){
          int row = lg*4 + j;
          int col = nfh*16 + lrow;
          *(unsigned short*)(Pw + (row*72 + col)*2) = f2bf(sacc[nf][j]);
        }
      }
      #pragma unroll
      for (int k2=0;k2<2;k2++){
        int ks2 = half*2 + k2;
        short8 pf, vf[4];
        pf = *(const short8*)(Pw + lrow*144 + lg*16 + k2*64);
        #pragma unroll
        for (int n2=0;n2<4;n2++){
          int d = n2*16+lrow;
          int kbb2 = lg + ks2*4;
          vf[n2] = *(const short8*)(smV + d*256 + ((kbb2^(d&7))<<4));
        }
        #pragma unroll
        for (int n2=0;n2<4;n2++)
          oacc[n2] = __builtin_amdgcn_mfma_f32_16x16x32_bf16(pf, vf[n2], oacc[n2], 0,0,0);
      }
    }
  }
  #pragma unroll
  for (int n2=0;n2<4;n2++){
    #pragma unroll
    for (int j=0;j<4;j++){
      float v = oacc[n2][j] / lrun[j];
      int qi = q0 + w*16 + lg*4 + j;
      int d = n2*16 + lrow;
      y[((size_t)(b*1024+qi))*512 + h*64 + d] = f2bf(v);
    }
  }
}

// ---------------------------------------------------------------------------
__global__ __launch_bounds__(256)
void router_topk(const float* __restrict__ x2f, const float* __restrict__ rw,
                 const float* __restrict__ rb, float* __restrict__ gates)
{
  int tkn = blockIdx.x*4 + (threadIdx.x>>6);
  int lane = threadIdx.x & 63;
  int e = lane & 15, p = lane >> 4;
  const float* xr = x2f + (size_t)tkn*512;
  float part = 0.f;
  for (int d = p*128; d < p*128+128; d++)
    part += xr[d] * rw[d*16 + e];
  part += __shfl_xor(part, 16);
  part += __shfl_xor(part, 32);
  float logit = part + rb[e];
  float mx = logit;
  #pragma unroll
  for (int m=1;m<16;m<<=1) mx = fmaxf(mx, __shfl_xor(mx, m));
  float ex = __expf(logit - mx);
  float sm = ex;
  #pragma unroll
  for (int m=1;m<16;m<<=1) sm += __shfl_xor(sm, m);
  float prob = ex / sm;
  bool taken = false;
  float ssum = 0.f;
  #pragma unroll
  for (int r=0;r<8;r++){
    float cv = taken ? -1.f : prob;
    int ci = e;
    #pragma unroll
    for (int m=1;m<16;m<<=1){
      float ov = __shfl_xor(cv, m);
      int oi = __shfl_xor(ci, m);
      if (ov > cv || (ov == cv && oi < ci)){ cv = ov; ci = oi; }
    }
    if (e == ci) taken = true;
    ssum += cv;
  }
  if (lane < 16)
    gates[(size_t)tkn*16 + e] = taken ? prob / ssum : 0.f;
}

// ---------------------------------------------------------------------------
__global__ void listbuild(const float* __restrict__ gates, int* __restrict__ list,
                          int* __restrict__ slot, int* __restrict__ cnt)
{
  int e = blockIdx.x;
  int tid = threadIdx.x, w = tid>>6, lane = tid&63;
  __shared__ int sbase;
  __shared__ int wsum[4];
  if (tid==0) sbase = 0;
  __syncthreads();
  for (int c=0;c<8;c++){
    int tk = c*256 + tid;
    bool flag = gates[(size_t)tk*16 + e] > 0.f;
    unsigned long long bal = __ballot(flag);
    if (lane==0) wsum[w] = (int)__popcll(bal);
    __syncthreads();
    int wpref = 0;
    for (int i=0;i<w;i++) wpref += wsum[i];
    int tot = wsum[0]+wsum[1]+wsum[2]+wsum[3];
    int lpref = (int)__popcll(bal & ((1ull<<lane)-1ull));
    if (flag){
      int pos = sbase + wpref + lpref;
      list[e*2048 + pos] = tk;
      slot[(size_t)tk*16 + e] = pos;
    }
    __syncthreads();
    if (tid==0) sbase += tot;
    __syncthreads();
  }
  if (tid==0) cnt[e] = sbase;
}

__global__ void prefix_off(const int* __restrict__ cnt, int* __restrict__ off){
  if (threadIdx.x==0 && blockIdx.x==0){
    int a=0;
    for (int e=0;e<16;e++){ off[e]=a; a+=cnt[e]; }
    off[16]=a;
  }
}

__global__ __launch_bounds__(256)
void gather_rows(const unsigned short* __restrict__ x2h, const int* __restrict__ list,
                 const int* __restrict__ cnt, const int* __restrict__ off,
                 unsigned short* __restrict__ xe)
{
  int e = blockIdx.y;
  int s = blockIdx.x*4 + (threadIdx.x>>6);
  if (s >= cnt[e]) return;
  int lane = threadIdx.x & 63;
  int tk = list[e*2048 + s];
  *(short8*)(xe + ((size_t)(off[e]+s))*512 + lane*8) =
      *(const short8*)(x2h + (size_t)tk*512 + lane*8);
}

__global__ __launch_bounds__(256)
void combine_k(const float* __restrict__ x2f, const unsigned short* __restrict__ eo,
               const float* __restrict__ gates, const int* __restrict__ slot,
               const int* __restrict__ off, float* __restrict__ out)
{
  int tkn = blockIdx.x;
  __shared__ float gs[16];
  __shared__ int rws[16];
  int tid = threadIdx.x;
  if (tid < 16){
    float g = gates[(size_t)tkn*16 + tid];
    gs[tid] = g;
    rws[tid] = (g > 0.f) ? (off[tid] + slot[(size_t)tkn*16 + tid]) : 0;
  }
  __syncthreads();
  for (int d = tid; d < 512; d += 256){
    float v = x2f[(size_t)tkn*512 + d];
    #pragma unroll
    for (int e=0;e<16;e++){
      float g = gs[e];
      if (g > 0.f) v += g * bf2f(eo[(size_t)rws[e]*512 + d]);
    }
    out[(size_t)tkn*512 + d] = v;
  }
}

// ---------------------------------------------------------------------------
extern "C" void kernel_launch(void* const* d_in, const int* in_sizes, int n_in,
                              void* d_out, int out_size, void* d_ws, size_t ws_size,
                              hipStream_t stream) {
  (void)in_sizes; (void)n_in; (void)out_size; (void)ws_size;
  const float* x    = (const float*)d_in[0];
  const float* gw   = (const float*)d_in[1];
  const float* bw   = (const float*)d_in[2];
  const float* caw  = (const float*)d_in[3];
  const float* cab  = (const float*)d_in[4];
  const float* alpha= (const float*)d_in[5];
  const float* cpw  = (const float*)d_in[6];
  const float* cpb  = (const float*)d_in[7];
  const float* rw   = (const float*)d_in[8];
  const float* rb   = (const float*)d_in[9];
  const float* w_in = (const float*)d_in[10];
  const float* b_in = (const float*)d_in[11];
  const float* w1   = (const float*)d_in[12];
  const float* b1   = (const float*)d_in[13];
  const float* w2   = (const float*)d_in[14];
  const float* b2   = (const float*)d_in[15];
  const float* w_out= (const float*)d_in[16];
  const float* b_out= (const float*)d_in[17];

  char* ws = (char*)d_ws;
  size_t o = 0;
  auto alloc = [&](size_t bytes)->char*{
    char* p = ws + o;
    o += (bytes + 255) & ~(size_t)255;
    return p;
  };
  const size_t PADROWS = 16896;  // 16384 + 256-tile overread pad
  unsigned short* wT_attn = (unsigned short*)alloc(1536ull*512*2);
  unsigned short* wT_proj = (unsigned short*)alloc(512ull*512*2);
  unsigned short* wT_in   = (unsigned short*)alloc(16ull*2048*512*2);
  unsigned short* wT1p    = (unsigned short*)alloc(16ull*4096*2048*2);
  unsigned short* wT_2    = (unsigned short*)alloc(16ull*2048*2048*2);
  unsigned short* wT_out  = (unsigned short*)alloc(16ull*512*2048*2);
  unsigned short* xn      = (unsigned short*)alloc(2048ull*512*2);
  unsigned short* q_s     = (unsigned short*)alloc(2048ull*512*2);
  unsigned short* k_hat   = (unsigned short*)alloc(2048ull*512*2);
  unsigned short* v_t     = (unsigned short*)alloc(2048ull*512*2);
  unsigned short* ybuf    = (unsigned short*)alloc(2048ull*512*2);
  float*          x2f     = (float*)alloc(2048ull*512*4);
  unsigned short* x2h     = (unsigned short*)alloc(2048ull*512*2);
  float*          gates   = (float*)alloc(2048ull*16*4);
  int*            slot    = (int*)alloc(2048ull*16*4);
  int*            list    = (int*)alloc(16ull*2048*4);
  int*            cnt     = (int*)alloc(64);
  int*            off     = (int*)alloc(256);
  unsigned short* xe      = (unsigned short*)alloc(PADROWS*512*2);   // + eo alias
  unsigned short* hbuf    = (unsigned short*)alloc(PADROWS*2048*2);  // + o alias
  unsigned short* sbuf    = (unsigned short*)alloc(PADROWS*2048*2);
  unsigned short* eobuf   = xe;   // xe dead after h-GEMM
  unsigned short* obuf    = hbuf; // hbuf dead after fused SwiGLU GEMM

  dim3 blk(256);
  dim3 blk5(512);
  // one merged prep dispatch (8-tile blocks): weight transposes + rmsnorm
  prep_all<<<29312, blk, 0, stream>>>(caw, cpw, w_in, w1, w2, w_out,
                                      wT_attn, wT_proj, wT_in, wT1p, wT_2, wT_out,
                                      x, gw, bw, xn);

  // qkv GEMM (128^2, 192 blocks) with fused head-norm epilogue
  gemm_qkv<<<dim3(12, 16), blk, 0, stream>>>(xn, wT_attn, cab, alpha,
                                             q_s, k_hat, v_t, 1536, 512);
  attn_k<<<dim3(16,16), blk, 0, stream>>>(q_s, k_hat, v_t, ybuf);
  gemm_proj<<<dim3(4,16,1), blk, 0, stream>>>(ybuf, wT_proj, cpb, x2f, x2h, x, 2048, 512, 512);
  router_topk<<<512, blk, 0, stream>>>(x2f, rw, rb, gates);
  listbuild<<<16, blk, 0, stream>>>(gates, list, slot, cnt);
  prefix_off<<<1, 64, 0, stream>>>(cnt, off);
  gather_rows<<<dim3(512,16), blk, 0, stream>>>(x2h, list, cnt, off, xe);

  // experts (batched over z = expert, rows compacted via off[])
  gemmT<1><<<dim3(8,8,16), blk5, 0, stream>>>(xe, wT_in, b_in, hbuf,
                                              0, 2048, 512, off, 2048ll*512, 2048);
  gemmT<2><<<dim3(16,8,16), blk5, 0, stream>>>(hbuf, wT1p, b1, sbuf,
                                               0, 4096, 2048, off, 4096ll*2048, 4096);
  gemmT<1><<<dim3(8,8,16), blk5, 0, stream>>>(sbuf, wT_2, b2, obuf,
                                              0, 2048, 2048, off, 2048ll*2048, 2048);
  gemmT<1><<<dim3(2,8,16), blk5, 0, stream>>>(obuf, wT_out, b_out, eobuf,
                                              0, 512, 2048, off, 512ll*2048, 512);
  combine_k<<<2048, blk, 0, stream>>>(x2f, eobuf, gates, slot, off, (float*)d_out);
}